// Round 6
// baseline (524.911 us; speedup 1.0000x reference)
//
#include <hip/hip_runtime.h>

#define N_USER 100000
#define N_ITEM 100000
#define N_NODES 200000
#define NNZ 6400000
#define EMB 64
#define BATCH 1024
#define B3 (3 * BATCH)   // 3072 output rows (users, pos, neg)

typedef __attribute__((ext_vector_type(8))) short bf16x8;   // 8 bf16 = 4 VGPRs
typedef __attribute__((ext_vector_type(4))) float f32x4;    // MFMA 16x16 acc
typedef __attribute__((ext_vector_type(4))) float fvec4;    // nt-load-able float4
typedef __attribute__((ext_vector_type(2))) unsigned int u32x2;  // nt-store-able uint2

// ---------------------------------------------------------------------------
// Frontier-sparsified NGCF, 6-launch schedule.
// Round-6 = round-5 with the ds_bpermute address fixed: byte addr must be
// (t + q)*4 == q4 + t*4 (round-5's (q4+t)*4 read lane 4q+t — wrong elements).
//   - spmm outputs stored NONTEMPORAL (keep L2 for ego_h gather lines)
//   - spmm chunk depth 64 (all 64 lanes load distinct col/val)
//   - shfl_up in row_ptr build
// Schedule:
//   K1 setup_fused      : row_ptr ∪ concat ∪ wfrag-pack ∪ layer0-gather ∪ zero
//   K2 spmm_full_flags  : layer-1 spmm (200k rows) + flag-set appendix
//   K3 dense_full_comp  : layer-1 dense (full) + ballot-compaction appendix
//   K4 spmm_list_norm1  : layer-2 spmm (active2) + layer-1 norm appendix
//   K5 dense_list       : layer-2 dense (list)
//   K6 layer3_norm2     : batch spmm->LDS -> dense -> leaky+L2norm + L2 norm
// ---------------------------------------------------------------------------

// f32 -> bf16 (RNE), raw ushort bits
__device__ __forceinline__ unsigned short f2bf(float f) {
    unsigned int b = __builtin_bit_cast(unsigned int, f);
    b += 0x7FFFu + ((b >> 16) & 1u);
    return (unsigned short)(b >> 16);
}
__device__ __forceinline__ float bf2f(unsigned short u) {
    return __builtin_bit_cast(float, (unsigned int)u << 16);
}
__device__ __forceinline__ unsigned int pack2(float lo, float hi) {
    return ((unsigned int)f2bf(hi) << 16) | f2bf(lo);
}

// elementwise product of two bf16 fragments (A-layouts align), f32 math
__device__ __forceinline__ bf16x8 mul_bf(bf16x8 a, bf16x8 b) {
    bf16x8 r;
#pragma unroll
    for (int j = 0; j < 8; ++j) {
        float f = bf2f((unsigned short)a[j]) * bf2f((unsigned short)b[j]);
        r[j] = (short)f2bf(f);
    }
    return r;
}

__device__ __forceinline__ int batch_node(const int* users, const int* pos,
                                          const int* neg, int b) {
    int t = b >> 10, idx = b & 1023;
    if (t == 0) return users[idx];
    if (t == 1) return N_USER + pos[idx];
    return N_USER + neg[idx];
}

// ---- K1: fused setup ------------------------------------------------------
#define SB_ROWPTR 25000                    // 25000*256 = 6.4M = NNZ
#define SB_CONCAT 12800                    // 12800*256 >= N_NODES*EMB/4
#define SB_WFRAG  12                       // 12*4 = 48 original wfrag blocks
#define SB_GATH0  768                      // 768*4  = 3072 layer-0 rows
#define SB_ZFLAG  784                      // 784*256 >= N_NODES+4
#define SETUP_BLOCKS (SB_ROWPTR + SB_CONCAT + SB_WFRAG + SB_GATH0 + SB_ZFLAG)

__global__ __launch_bounds__(256) void setup_fused(
        const int* __restrict__ row, const float* __restrict__ ue,
        const float* __restrict__ ie,
        const float* __restrict__ W0, const float* __restrict__ W1,
        const float* __restrict__ W2, const float* __restrict__ W3,
        const float* __restrict__ W4, const float* __restrict__ W5,
        const int* __restrict__ users, const int* __restrict__ pos,
        const int* __restrict__ neg,
        int* __restrict__ row_ptr, unsigned short* __restrict__ ego_h,
        unsigned short* __restrict__ wfrag, float* __restrict__ out,
        int* __restrict__ flags) {
    unsigned bx = blockIdx.x;
    int tx = threadIdx.x;
    if (bx < SB_ROWPTR) {
        // row_ptr[r] = lower_bound(adj_row, r); prev via shfl_up (lane 0 loads)
        int i = bx * 256 + tx;
        int lane = tx & 63;
        int b = __builtin_nontemporal_load(row + i);
        int a = __shfl_up(b, 1);
        if (lane == 0) a = (i == 0) ? -1 : row[i - 1];
        for (int r = a + 1; r <= b; ++r) row_ptr[r] = i;
        if (i == NNZ - 1)
            for (int r = b + 1; r <= N_NODES; ++r) row_ptr[r] = NNZ;
        return;
    }
    bx -= SB_ROWPTR;
    if (bx < SB_CONCAT) {
        // ego_h = bf16([ue ; ie]); float4 in, 4xbf16 out (ego_h stays cached:
        // it is the gather target of K2 — do NOT nt-store it)
        int i = bx * 256 + tx;
        const int nu4 = N_USER * EMB / 4;
        const int tot4 = N_NODES * EMB / 4;
        if (i < tot4) {
            fvec4 v = (i < nu4) ? __builtin_nontemporal_load((const fvec4*)ue + i)
                                : __builtin_nontemporal_load((const fvec4*)ie + (i - nu4));
            u32x2 o;
            o.x = pack2(v.x, v.y);
            o.y = pack2(v.z, v.w);
            ((u32x2*)ego_h)[i] = o;
        }
        return;
    }
    bx -= SB_CONCAT;
    if (bx < SB_WFRAG) {
        // pack 6 64x64 f32 weights into MFMA B-fragment bf16 layout
        int ob = bx * 4 + (tx >> 6);       // original block id 0..47
        int l = tx & 63;
        int m = ob >> 3, t = (ob >> 1) & 3, c = ob & 1;
        const float* W = m == 0 ? W0 : m == 1 ? W1 : m == 2 ? W2
                       : m == 3 ? W3 : m == 4 ? W4 : W5;
        int quad = l >> 4, n = l & 15;
        unsigned short* dst = wfrag + ((size_t)ob * 64 + l) * 8;
#pragma unroll
        for (int j = 0; j < 8; ++j)
            dst[j] = f2bf(W[(c * 32 + quad * 8 + j) * 64 + t * 16 + n]);
        return;
    }
    bx -= SB_WFRAG;
    if (bx < SB_GATH0) {
        // layer-0 output columns: exact f32 from the input embeddings
        int b = bx * 4 + (tx >> 6);
        int lane = tx & 63;
        int node = batch_node(users, pos, neg, b);
        float v = (node < N_USER) ? ue[(size_t)node * EMB + lane]
                                  : ie[(size_t)(node - N_USER) * EMB + lane];
        out[(size_t)b * 256 + lane] = v;
        return;
    }
    bx -= SB_GATH0;
    {   // zero flags + cnt
        int i = bx * 256 + tx;
        if (i < N_NODES + 4) flags[i] = 0;
    }
}

// ---- SpMM core ------------------------------------------------------------
// CSR SpMM, quarter-wave gather: wave = 1 row; 16 lanes x uint2 (4 dims) cover
// the 64-dim row, so ONE dwordx2 gather serves 4 nnz. Chunk of 64 (col,val)
// staged coalesced (all 64 lanes distinct); at step t quarter q handles chunk
// element t+q via ds_bpermute byte addr (t+q)*4 = q4 + t*4. NT=true streams
// the output (global dst, consumed linearly next kernel — keep L2 for the
// ego gather lines); NT=false for LDS dst.
template <bool NT>
__device__ __forceinline__ void spmm_row(
        int row, int lane, const int* __restrict__ row_ptr,
        const int* __restrict__ col, const float* __restrict__ val,
        const unsigned short* __restrict__ xh, unsigned short* dst) {
    int q = lane >> 4, p = lane & 15;
    int q4 = q << 2;
    unsigned p4 = (unsigned)p * 4u;
    int j0 = row_ptr[row], j1 = row_ptr[row + 1];
    float a0 = 0.f, a1 = 0.f, a2 = 0.f, a3 = 0.f;
    for (int j = j0; j < j1; j += 64) {
        int jl = j + lane;
        bool ok = jl < j1;
        int cc = ok ? __builtin_nontemporal_load(col + jl) : 0;
        int vv = ok ? __builtin_bit_cast(int, __builtin_nontemporal_load(val + jl))
                    : 0;
        int n = j1 - j;
#pragma unroll
        for (int t = 0; t < 64; t += 4) {     // this step: nnz t..t+3
            if (t >= n) break;                // wave-uniform exit
            int   ct = __builtin_amdgcn_ds_bpermute(q4 + t * 4, cc);
            float vt = __builtin_bit_cast(float,
                        __builtin_amdgcn_ds_bpermute(q4 + t * 4, vv));
            unsigned idx = (unsigned)ct * 64u + p4;   // ushort index
            u32x2 d = *(const u32x2*)(xh + idx);
            float f0 = __builtin_bit_cast(float, d.x << 16);
            float f1 = __builtin_bit_cast(float, d.x & 0xffff0000u);
            float f2 = __builtin_bit_cast(float, d.y << 16);
            float f3 = __builtin_bit_cast(float, d.y & 0xffff0000u);
            a0 = fmaf(vt, f0, a0);
            a1 = fmaf(vt, f1, a1);
            a2 = fmaf(vt, f2, a2);
            a3 = fmaf(vt, f3, a3);
        }
    }
    a0 += __shfl_xor(a0, 16); a0 += __shfl_xor(a0, 32);
    a1 += __shfl_xor(a1, 16); a1 += __shfl_xor(a1, 32);
    a2 += __shfl_xor(a2, 16); a2 += __shfl_xor(a2, 32);
    a3 += __shfl_xor(a3, 16); a3 += __shfl_xor(a3, 32);
    if (q == 0) {
        u32x2 o;
        o.x = pack2(a0, a1);
        o.y = pack2(a2, a3);
        if constexpr (NT)
            __builtin_nontemporal_store(o, (u32x2*)dst + p);
        else
            ((u32x2*)dst)[p] = o;           // 16 lanes x 8B = full row
    }
}

#define SPMM_BLOCKS (N_NODES / 4)          // 50000

// K2: layer-1 full spmm + flag-set appendix (PLAIN stores — no atomics;
// races write the same value, dedupe happens at compaction).
__global__ __launch_bounds__(256) void spmm_full_flags(
        const int* __restrict__ row_ptr, const int* __restrict__ col,
        const float* __restrict__ val, const unsigned short* __restrict__ xh,
        unsigned short* __restrict__ yh, const int* __restrict__ users,
        const int* __restrict__ pos, const int* __restrict__ neg,
        int* __restrict__ flags) {
    int lane = threadIdx.x & 63;
    if (blockIdx.x < SPMM_BLOCKS) {
        int wave = (blockIdx.x * 256 + threadIdx.x) >> 6;
        spmm_row<true>(wave, lane, row_ptr, col, val, xh, yh + (size_t)wave * EMB);
        return;
    }
    // wave = one batch entry; mark node + all its neighbors
    int w = (blockIdx.x - SPMM_BLOCKS) * 4 + (threadIdx.x >> 6);
    int node = batch_node(users, pos, neg, w);
    if (lane == 0) flags[node] = 1;
    int j0 = row_ptr[node], j1 = row_ptr[node + 1];
    for (int j = j0 + lane; j < j1; j += 64) flags[col[j]] = 1;
}

// ---- dense layer core -----------------------------------------------------
// acc[t] = bias + side@Wgc[:,t] + (ego*side)@Wbi[:,t]; 16 rows x 64 cols/wave.
__device__ __forceinline__ void dense_core(
        const unsigned short* aside, const unsigned short* aego,
        const unsigned short* __restrict__ wf, int lane,
        const float* __restrict__ bgc, const float* __restrict__ bbi,
        f32x4 acc[4]) {
    int quad = lane >> 4, n = lane & 15;

    bf16x8 bfrag[2][4][2];
#pragma unroll
    for (int m = 0; m < 2; ++m)
#pragma unroll
        for (int t = 0; t < 4; ++t)
#pragma unroll
            for (int c = 0; c < 2; ++c)
                bfrag[m][t][c] = *(const bf16x8*)(wf + ((size_t)((m * 4 + t) * 2 + c) * 64 + lane) * 8);

#pragma unroll
    for (int t = 0; t < 4; ++t) {
        float bs = bgc[t * 16 + n] + bbi[t * 16 + n];
        acc[t] = (f32x4){bs, bs, bs, bs};
    }

    bf16x8 as0 = *(const bf16x8*)(aside + quad * 8);
    bf16x8 as1 = *(const bf16x8*)(aside + quad * 8 + 32);
    bf16x8 ae0 = *(const bf16x8*)(aego + quad * 8);
    bf16x8 ae1 = *(const bf16x8*)(aego + quad * 8 + 32);
    bf16x8 ap0 = mul_bf(ae0, as0);
    bf16x8 ap1 = mul_bf(ae1, as1);

#pragma unroll
    for (int t = 0; t < 4; ++t) {
        acc[t] = __builtin_amdgcn_mfma_f32_16x16x32_bf16(as0, bfrag[0][t][0], acc[t], 0, 0, 0);
        acc[t] = __builtin_amdgcn_mfma_f32_16x16x32_bf16(as1, bfrag[0][t][1], acc[t], 0, 0, 0);
        acc[t] = __builtin_amdgcn_mfma_f32_16x16x32_bf16(ap0, bfrag[1][t][0], acc[t], 0, 0, 0);
        acc[t] = __builtin_amdgcn_mfma_f32_16x16x32_bf16(ap1, bfrag[1][t][1], acc[t], 0, 0, 0);
    }
}

#define DENSE_BLOCKS (N_NODES / 64)        // 3125
#define COMPACT_BLOCKS ((N_NODES + 255) / 256)   // 782

// K3: layer-1 dense (full, in-place) + ballot-compaction appendix.
// Compaction: one atomicAdd per wave (popcount), in-wave prefix via ballot.
__global__ __launch_bounds__(256) void dense_full_compact(
        const unsigned short* __restrict__ side_h,
        unsigned short* __restrict__ ego_h,
        const unsigned short* __restrict__ wf,
        const float* __restrict__ bgc, const float* __restrict__ bbi,
        const int* __restrict__ flags, int* __restrict__ list2,
        int* __restrict__ cnt) {
    int lane = threadIdx.x & 63;
    if (blockIdx.x >= DENSE_BLOCKS) {
        int i = (blockIdx.x - DENSE_BLOCKS) * 256 + threadIdx.x;   // node id
        bool set = (i < N_NODES) && (flags[i] != 0);
        unsigned long long m = __ballot(set);
        int pc = __popcll(m);
        if (pc) {
            int base = 0;
            if (lane == 0) base = atomicAdd(cnt, pc);
            base = __shfl(base, 0);
            if (set) list2[base + __popcll(m & ((1ull << lane) - 1ull))] = i;
        }
        return;
    }
    int wave = threadIdx.x >> 6;
    int quad = lane >> 4, n = lane & 15;
    int base = (blockIdx.x * 4 + wave) * 16;
    int rA = base + n;

    f32x4 acc[4];
    dense_core(side_h + (size_t)rA * EMB, ego_h + (size_t)rA * EMB,
               wf, lane, bgc, bbi, acc);

    // epilogue: C/D layout col=lane&15, row=quad*4+reg (m89-verified)
#pragma unroll
    for (int t = 0; t < 4; ++t)
#pragma unroll
        for (int i = 0; i < 4; ++i) {
            float v = acc[t][i];
            float o = v > 0.f ? v : 0.2f * v;
            ego_h[(size_t)(base + quad * 4 + i) * EMB + t * 16 + n] = f2bf(o);
        }
}

// K4: layer-2 list spmm + layer-1 gather_norm appendix blocks
__global__ __launch_bounds__(256) void spmm_list_norm1(
        const int* __restrict__ row_ptr, const int* __restrict__ col,
        const float* __restrict__ val, const unsigned short* __restrict__ xh,
        unsigned short* __restrict__ yh, const int* __restrict__ list,
        const int* __restrict__ cntp, const int* __restrict__ users,
        const int* __restrict__ pos, const int* __restrict__ neg,
        float* __restrict__ out) {
    int lane = threadIdx.x & 63;
    if (blockIdx.x < SPMM_BLOCKS) {
        int wave = (blockIdx.x * 256 + threadIdx.x) >> 6;
        if (wave >= *cntp) return;          // wave-uniform early exit
        int row = list[wave];
        spmm_row<true>(row, lane, row_ptr, col, val, xh, yh + (size_t)row * EMB);
        return;
    }
    // layer-1 norm: reads ego_h (xh) post-dense-1
    int b = (blockIdx.x - SPMM_BLOCKS) * 4 + (threadIdx.x >> 6);
    int node = batch_node(users, pos, neg, b);
    float v = bf2f(xh[(size_t)node * EMB + lane]);
    float s = v * v;
#pragma unroll
    for (int off = 32; off > 0; off >>= 1) s += __shfl_xor(s, off);
    float nn = fmaxf(sqrtf(s), 1e-12f);
    out[(size_t)b * 256 + 1 * EMB + lane] = v / nn;
}

// K5: layer-2 dense, list-sparsified in-place ego update. list is deduped so
// each row is owned by exactly one wave (in-place safe). Tail wave clamps.
__global__ __launch_bounds__(256) void dense_list(
        const unsigned short* __restrict__ side_h,
        unsigned short* __restrict__ ego_h,
        const unsigned short* __restrict__ wf,
        const float* __restrict__ bgc, const float* __restrict__ bbi,
        const int* __restrict__ list, const int* __restrict__ cntp) {
    int wave = threadIdx.x >> 6;
    int lane = threadIdx.x & 63;
    int quad = lane >> 4, n = lane & 15;
    int base = (blockIdx.x * 4 + wave) * 16;
    int cntv = *cntp;
    if (base >= cntv) return;

    int rA = base + n;
    rA = list[rA < cntv ? rA : cntv - 1];

    f32x4 acc[4];
    dense_core(side_h + (size_t)rA * EMB, ego_h + (size_t)rA * EMB,
               wf, lane, bgc, bbi, acc);

    int rw[4];
#pragma unroll
    for (int i = 0; i < 4; ++i) {
        int r = base + quad * 4 + i;
        rw[i] = (r < cntv) ? list[r] : -1;
    }
#pragma unroll
    for (int t = 0; t < 4; ++t)
#pragma unroll
        for (int i = 0; i < 4; ++i) {
            if (rw[i] < 0) continue;
            float v = acc[t][i];
            float o = v > 0.f ? v : 0.2f * v;
            ego_h[(size_t)rw[i] * EMB + t * 16 + n] = f2bf(o);
        }
}

// K6: fused layer-3 (spmm->LDS -> dense -> leaky+L2norm -> out) + layer-2
// norm appendix blocks. LDS row stride 72 shorts (144B): 16B-aligned rows,
// <=2-way bank aliasing (free per m136).
#define L3_BLOCKS (B3 / 64)                // 48
__global__ __launch_bounds__(256) void layer3_norm2(
        const int* __restrict__ row_ptr, const int* __restrict__ col,
        const float* __restrict__ val, const unsigned short* __restrict__ ego_h,
        const int* __restrict__ users, const int* __restrict__ pos,
        const int* __restrict__ neg, const unsigned short* __restrict__ wf,
        const float* __restrict__ bgc, const float* __restrict__ bbi,
        float* __restrict__ out) {
    __shared__ unsigned short sside[64 * 72];   // 9216 B
    int lane = threadIdx.x & 63;
    if (blockIdx.x >= L3_BLOCKS) {
        // layer-2 norm: reads ego_h post-dense-2
        int b = (blockIdx.x - L3_BLOCKS) * 4 + (threadIdx.x >> 6);
        int node = batch_node(users, pos, neg, b);
        float v = bf2f(ego_h[(size_t)node * EMB + lane]);
        float s = v * v;
#pragma unroll
        for (int off = 32; off > 0; off >>= 1) s += __shfl_xor(s, off);
        float nn = fmaxf(sqrtf(s), 1e-12f);
        out[(size_t)b * 256 + 2 * EMB + lane] = v / nn;
        return;
    }
    int wave = threadIdx.x >> 6;
    int b0 = blockIdx.x * 64;
    // phase 1: each wave spmm's 16 batch rows into LDS (dupes benign:
    // different LDS slots, identical values). ego_h is read-only here.
    for (int r = 0; r < 16; ++r) {
        int bpos = b0 + wave * 16 + r;
        int node = batch_node(users, pos, neg, bpos);
        spmm_row<false>(node, lane, row_ptr, col, val, ego_h,
                        &sside[(wave * 16 + r) * 72]);
    }
    __syncthreads();
    // phase 2: dense on this wave's 16 rows, A-side from LDS
    int quad = lane >> 4, n = lane & 15;
    int nodeA = batch_node(users, pos, neg, b0 + wave * 16 + n);
    f32x4 acc[4];
    dense_core(&sside[(wave * 16 + n) * 72], ego_h + (size_t)nodeA * EMB,
               wf, lane, bgc, bbi, acc);
    // fused epilogue: leaky, per-row L2 norm (row quad*4+i lives in the 16
    // lanes of this quad: reduce over n via xor 1,2,4,8), write cols 192..255
    float ov[4][4];
#pragma unroll
    for (int t = 0; t < 4; ++t)
#pragma unroll
        for (int i = 0; i < 4; ++i) {
            float v = acc[t][i];
            ov[t][i] = v > 0.f ? v : 0.2f * v;
        }
#pragma unroll
    for (int i = 0; i < 4; ++i) {
        float s = ov[0][i] * ov[0][i] + ov[1][i] * ov[1][i]
                + ov[2][i] * ov[2][i] + ov[3][i] * ov[3][i];
        s += __shfl_xor(s, 1); s += __shfl_xor(s, 2);
        s += __shfl_xor(s, 4); s += __shfl_xor(s, 8);
        float ninv = 1.f / fmaxf(sqrtf(s), 1e-12f);
        int bpos = b0 + wave * 16 + quad * 4 + i;
#pragma unroll
        for (int t = 0; t < 4; ++t)
            out[(size_t)bpos * 256 + 192 + t * 16 + n] = ov[t][i] * ninv;
    }
}

extern "C" void kernel_launch(void* const* d_in, const int* in_sizes, int n_in,
                              void* d_out, int out_size, void* d_ws, size_t ws_size,
                              hipStream_t stream) {
    const int*   users    = (const int*)d_in[0];
    const int*   pos      = (const int*)d_in[1];
    const int*   neg      = (const int*)d_in[2];
    const int*   adj_row  = (const int*)d_in[3];
    const int*   adj_col  = (const int*)d_in[4];
    const float* adj_val  = (const float*)d_in[5];
    const float* user_emb = (const float*)d_in[6];
    const float* item_emb = (const float*)d_in[7];
    // d_in[8..19]: W_gc_0, b_gc_0, W_bi_0, b_bi_0, W_gc_1, ... (4 per layer)

    unsigned short* ego_h   = (unsigned short*)d_ws;
    unsigned short* side_h  = ego_h + (size_t)N_NODES * EMB;
    int*            row_ptr = (int*)(side_h + (size_t)N_NODES * EMB);
    unsigned short* wfrag   = (unsigned short*)(row_ptr + 200704);  // 16B-aligned
    int*            flags   = (int*)(wfrag + 6 * 8 * 64 * 8);       // 49152B -> aligned
    int*            cnt     = flags + N_NODES;                       // +4 ints pad
    int*            list2   = cnt + 4;
    float*          out     = (float*)d_out;

    // K1: all setup work in one dispatch
    setup_fused<<<SETUP_BLOCKS, 256, 0, stream>>>(
        adj_row, user_emb, item_emb,
        (const float*)d_in[8],  (const float*)d_in[10], (const float*)d_in[12],
        (const float*)d_in[14], (const float*)d_in[16], (const float*)d_in[18],
        users, pos, neg, row_ptr, ego_h, wfrag, out, flags);

    // K2: layer-1 spmm + flag-set (plain stores)
    spmm_full_flags<<<SPMM_BLOCKS + B3 / 4, 256, 0, stream>>>(
        row_ptr, adj_col, adj_val, ego_h, side_h, users, pos, neg, flags);

    // K3: layer-1 dense (full, in-place) + ballot-compaction of flags->list2
    dense_full_compact<<<DENSE_BLOCKS + COMPACT_BLOCKS, 256, 0, stream>>>(
        side_h, ego_h, wfrag, (const float*)d_in[9], (const float*)d_in[11],
        flags, list2, cnt);

    // K4: layer-2 spmm (active2) + layer-1 norm
    spmm_list_norm1<<<SPMM_BLOCKS + B3 / 4, 256, 0, stream>>>(
        row_ptr, adj_col, adj_val, ego_h, side_h, list2, cnt,
        users, pos, neg, out);

    // K5: layer-2 dense (list, in-place)
    dense_list<<<DENSE_BLOCKS, 256, 0, stream>>>(
        side_h, ego_h, wfrag + (size_t)1 * 2 * 8 * 64 * 8,
        (const float*)d_in[13], (const float*)d_in[15], list2, cnt);

    // K6: fused layer-3 + layer-2 norm
    layer3_norm2<<<L3_BLOCKS + B3 / 4, 256, 0, stream>>>(
        row_ptr, adj_col, adj_val, ego_h, users, pos, neg,
        wfrag + (size_t)2 * 2 * 8 * 64 * 8,
        (const float*)d_in[17], (const float*)d_in[19], out);
}

// Round 7
// 474.925 us; speedup vs baseline: 1.1053x; 1.1053x over previous
//
#include <hip/hip_runtime.h>

#define N_USER 100000
#define N_ITEM 100000
#define N_NODES 200000
#define NNZ 6400000
#define EMB 64
#define BATCH 1024
#define B3 (3 * BATCH)   // 3072 output rows (users, pos, neg)

typedef __attribute__((ext_vector_type(8))) short bf16x8;   // 8 bf16 = 4 VGPRs
typedef __attribute__((ext_vector_type(4))) float f32x4;    // MFMA 16x16 acc

// ---------------------------------------------------------------------------
// Frontier-sparsified NGCF, 6-launch schedule. Round-7 = exact round-3 code
// (best measured: 475.3 us). Round-6's nt-store + chunk-64 spmm regressed
// (129->149 us, FETCH only -3.6%) and is reverted verbatim.
// spmm roofline note: 819 MB gather demand in ~129 us = 6.35 TB/s effective
// (~485 MB L2-hit @ ~34 TB/s + ~334 MB HBM-miss @ ~3.3 TB/s) — the kernel is
// HBM-random-miss-bound; col-partitioning (partial-sum traffic) and fp8
// (absmax budget) are both ruled out.
// Schedule:
//   K1 setup_fused      : row_ptr ∪ concat ∪ wfrag-pack ∪ layer0-gather ∪ zero
//   K2 spmm_full_flags  : layer-1 spmm (200k rows) + flag-set appendix
//   K3 dense_full_comp  : layer-1 dense (full) + ballot-compaction appendix
//   K4 spmm_list_norm1  : layer-2 spmm (active2) + layer-1 norm appendix
//   K5 dense_list       : layer-2 dense (list)
//   K6 layer3_norm2     : batch spmm->LDS -> dense -> leaky+L2norm + L2 norm
// active2 = batch ∪ neighbors(batch) (~78k rows), deduped so the in-place
// dense is race-free. All grids static (graph-capture safe).
// ---------------------------------------------------------------------------

// f32 -> bf16 (RNE), raw ushort bits
__device__ __forceinline__ unsigned short f2bf(float f) {
    unsigned int b = __builtin_bit_cast(unsigned int, f);
    b += 0x7FFFu + ((b >> 16) & 1u);
    return (unsigned short)(b >> 16);
}
__device__ __forceinline__ float bf2f(unsigned short u) {
    return __builtin_bit_cast(float, (unsigned int)u << 16);
}
__device__ __forceinline__ unsigned int pack2(float lo, float hi) {
    return ((unsigned int)f2bf(hi) << 16) | f2bf(lo);
}

// elementwise product of two bf16 fragments (A-layouts align), f32 math
__device__ __forceinline__ bf16x8 mul_bf(bf16x8 a, bf16x8 b) {
    bf16x8 r;
#pragma unroll
    for (int j = 0; j < 8; ++j) {
        float f = bf2f((unsigned short)a[j]) * bf2f((unsigned short)b[j]);
        r[j] = (short)f2bf(f);
    }
    return r;
}

__device__ __forceinline__ int batch_node(const int* users, const int* pos,
                                          const int* neg, int b) {
    int t = b >> 10, idx = b & 1023;
    if (t == 0) return users[idx];
    if (t == 1) return N_USER + pos[idx];
    return N_USER + neg[idx];
}

// ---- K1: fused setup ------------------------------------------------------
#define SB_ROWPTR 25000                    // 25000*256 = 6.4M = NNZ
#define SB_CONCAT 12800                    // 12800*256 >= N_NODES*EMB/4
#define SB_WFRAG  12                       // 12*4 = 48 original wfrag blocks
#define SB_GATH0  768                      // 768*4  = 3072 layer-0 rows
#define SB_ZFLAG  784                      // 784*256 >= N_NODES+4
#define SETUP_BLOCKS (SB_ROWPTR + SB_CONCAT + SB_WFRAG + SB_GATH0 + SB_ZFLAG)

__global__ __launch_bounds__(256) void setup_fused(
        const int* __restrict__ row, const float* __restrict__ ue,
        const float* __restrict__ ie,
        const float* __restrict__ W0, const float* __restrict__ W1,
        const float* __restrict__ W2, const float* __restrict__ W3,
        const float* __restrict__ W4, const float* __restrict__ W5,
        const int* __restrict__ users, const int* __restrict__ pos,
        const int* __restrict__ neg,
        int* __restrict__ row_ptr, unsigned short* __restrict__ ego_h,
        unsigned short* __restrict__ wfrag, float* __restrict__ out,
        int* __restrict__ flags) {
    unsigned bx = blockIdx.x;
    int tx = threadIdx.x;
    if (bx < SB_ROWPTR) {
        // row_ptr[r] = lower_bound(adj_row, r)
        int i = bx * 256 + tx;
        int b = row[i];
        int a = (i == 0) ? -1 : row[i - 1];
        for (int r = a + 1; r <= b; ++r) row_ptr[r] = i;
        if (i == NNZ - 1)
            for (int r = b + 1; r <= N_NODES; ++r) row_ptr[r] = NNZ;
        return;
    }
    bx -= SB_ROWPTR;
    if (bx < SB_CONCAT) {
        // ego_h = bf16([ue ; ie]); float4 in, 4xbf16 out
        int i = bx * 256 + tx;
        const int nu4 = N_USER * EMB / 4;
        const int tot4 = N_NODES * EMB / 4;
        if (i < tot4) {
            float4 v = (i < nu4) ? ((const float4*)ue)[i] : ((const float4*)ie)[i - nu4];
            uint2 o;
            o.x = pack2(v.x, v.y);
            o.y = pack2(v.z, v.w);
            ((uint2*)ego_h)[i] = o;
        }
        return;
    }
    bx -= SB_CONCAT;
    if (bx < SB_WFRAG) {
        // pack 6 64x64 f32 weights into MFMA B-fragment bf16 layout
        int ob = bx * 4 + (tx >> 6);       // original block id 0..47
        int l = tx & 63;
        int m = ob >> 3, t = (ob >> 1) & 3, c = ob & 1;
        const float* W = m == 0 ? W0 : m == 1 ? W1 : m == 2 ? W2
                       : m == 3 ? W3 : m == 4 ? W4 : W5;
        int quad = l >> 4, n = l & 15;
        unsigned short* dst = wfrag + ((size_t)ob * 64 + l) * 8;
#pragma unroll
        for (int j = 0; j < 8; ++j)
            dst[j] = f2bf(W[(c * 32 + quad * 8 + j) * 64 + t * 16 + n]);
        return;
    }
    bx -= SB_WFRAG;
    if (bx < SB_GATH0) {
        // layer-0 output columns: exact f32 from the input embeddings
        int b = bx * 4 + (tx >> 6);
        int lane = tx & 63;
        int node = batch_node(users, pos, neg, b);
        float v = (node < N_USER) ? ue[(size_t)node * EMB + lane]
                                  : ie[(size_t)(node - N_USER) * EMB + lane];
        out[(size_t)b * 256 + lane] = v;
        return;
    }
    bx -= SB_GATH0;
    {   // zero flags + cnt
        int i = bx * 256 + tx;
        if (i < N_NODES + 4) flags[i] = 0;
    }
}

// ---- SpMM core ------------------------------------------------------------
// CSR SpMM, quarter-wave gather: wave = 1 row; 16 lanes x uint2 (4 dims) cover
// the 64-dim row, so ONE dwordx2 gather serves 4 nnz. Chunk of 32 (col,val)
// staged coalesced, per-quarter broadcast via ds_bpermute. dst may be LDS.
__device__ __forceinline__ void spmm_row(
        int row, int lane, const int* __restrict__ row_ptr,
        const int* __restrict__ col, const float* __restrict__ val,
        const unsigned short* __restrict__ xh, unsigned short* dst) {
    int q = lane >> 4, p = lane & 15;
    int q4 = q << 2;
    unsigned p4 = (unsigned)p * 4u;
    int j0 = row_ptr[row], j1 = row_ptr[row + 1];
    float a0 = 0.f, a1 = 0.f, a2 = 0.f, a3 = 0.f;
    for (int j = j0; j < j1; j += 32) {
        int jl = j + (lane & 31);           // lanes 32..63 duplicate 0..31
        bool ok = jl < j1;
        int cc = ok ? __builtin_nontemporal_load(col + jl) : 0;
        int vv = ok ? __builtin_bit_cast(int, __builtin_nontemporal_load(val + jl))
                    : 0;
        int n = j1 - j;
#pragma unroll
        for (int g = 0; g < 4; ++g) {
            if (g * 8 >= n) break;          // wave-uniform exit
#pragma unroll
            for (int s = 0; s < 2; ++s) {
                const int t = g * 8 + s * 4;          // this step: nnz t..t+3
                int   ct = __builtin_amdgcn_ds_bpermute(q4 + t * 4, cc);
                float vt = __builtin_bit_cast(float,
                            __builtin_amdgcn_ds_bpermute(q4 + t * 4, vv));
                unsigned idx = (unsigned)ct * 64u + p4;   // ushort index
                uint2 d = *(const uint2*)(xh + idx);
                float f0 = __builtin_bit_cast(float, d.x << 16);
                float f1 = __builtin_bit_cast(float, d.x & 0xffff0000u);
                float f2 = __builtin_bit_cast(float, d.y << 16);
                float f3 = __builtin_bit_cast(float, d.y & 0xffff0000u);
                a0 = fmaf(vt, f0, a0);
                a1 = fmaf(vt, f1, a1);
                a2 = fmaf(vt, f2, a2);
                a3 = fmaf(vt, f3, a3);
            }
        }
    }
    a0 += __shfl_xor(a0, 16); a0 += __shfl_xor(a0, 32);
    a1 += __shfl_xor(a1, 16); a1 += __shfl_xor(a1, 32);
    a2 += __shfl_xor(a2, 16); a2 += __shfl_xor(a2, 32);
    a3 += __shfl_xor(a3, 16); a3 += __shfl_xor(a3, 32);
    if (q == 0) {
        uint2 o;
        o.x = pack2(a0, a1);
        o.y = pack2(a2, a3);
        ((uint2*)dst)[p] = o;               // 16 lanes x 8B = full row
    }
}

#define SPMM_BLOCKS (N_NODES / 4)          // 50000

// K2: layer-1 full spmm + flag-set appendix (PLAIN stores — no atomics;
// races write the same value, dedupe happens at compaction).
__global__ __launch_bounds__(256) void spmm_full_flags(
        const int* __restrict__ row_ptr, const int* __restrict__ col,
        const float* __restrict__ val, const unsigned short* __restrict__ xh,
        unsigned short* __restrict__ yh, const int* __restrict__ users,
        const int* __restrict__ pos, const int* __restrict__ neg,
        int* __restrict__ flags) {
    int lane = threadIdx.x & 63;
    if (blockIdx.x < SPMM_BLOCKS) {
        int wave = (blockIdx.x * 256 + threadIdx.x) >> 6;
        spmm_row(wave, lane, row_ptr, col, val, xh, yh + (size_t)wave * EMB);
        return;
    }
    // wave = one batch entry; mark node + all its neighbors
    int w = (blockIdx.x - SPMM_BLOCKS) * 4 + (threadIdx.x >> 6);
    int node = batch_node(users, pos, neg, w);
    if (lane == 0) flags[node] = 1;
    int j0 = row_ptr[node], j1 = row_ptr[node + 1];
    for (int j = j0 + lane; j < j1; j += 64) flags[col[j]] = 1;
}

// ---- dense layer core -----------------------------------------------------
// acc[t] = bias + side@Wgc[:,t] + (ego*side)@Wbi[:,t]; 16 rows x 64 cols/wave.
__device__ __forceinline__ void dense_core(
        const unsigned short* aside, const unsigned short* aego,
        const unsigned short* __restrict__ wf, int lane,
        const float* __restrict__ bgc, const float* __restrict__ bbi,
        f32x4 acc[4]) {
    int quad = lane >> 4, n = lane & 15;

    bf16x8 bfrag[2][4][2];
#pragma unroll
    for (int m = 0; m < 2; ++m)
#pragma unroll
        for (int t = 0; t < 4; ++t)
#pragma unroll
            for (int c = 0; c < 2; ++c)
                bfrag[m][t][c] = *(const bf16x8*)(wf + ((size_t)((m * 4 + t) * 2 + c) * 64 + lane) * 8);

#pragma unroll
    for (int t = 0; t < 4; ++t) {
        float bs = bgc[t * 16 + n] + bbi[t * 16 + n];
        acc[t] = (f32x4){bs, bs, bs, bs};
    }

    bf16x8 as0 = *(const bf16x8*)(aside + quad * 8);
    bf16x8 as1 = *(const bf16x8*)(aside + quad * 8 + 32);
    bf16x8 ae0 = *(const bf16x8*)(aego + quad * 8);
    bf16x8 ae1 = *(const bf16x8*)(aego + quad * 8 + 32);
    bf16x8 ap0 = mul_bf(ae0, as0);
    bf16x8 ap1 = mul_bf(ae1, as1);

#pragma unroll
    for (int t = 0; t < 4; ++t) {
        acc[t] = __builtin_amdgcn_mfma_f32_16x16x32_bf16(as0, bfrag[0][t][0], acc[t], 0, 0, 0);
        acc[t] = __builtin_amdgcn_mfma_f32_16x16x32_bf16(as1, bfrag[0][t][1], acc[t], 0, 0, 0);
        acc[t] = __builtin_amdgcn_mfma_f32_16x16x32_bf16(ap0, bfrag[1][t][0], acc[t], 0, 0, 0);
        acc[t] = __builtin_amdgcn_mfma_f32_16x16x32_bf16(ap1, bfrag[1][t][1], acc[t], 0, 0, 0);
    }
}

#define DENSE_BLOCKS (N_NODES / 64)        // 3125
#define COMPACT_BLOCKS ((N_NODES + 255) / 256)   // 782

// K3: layer-1 dense (full, in-place) + ballot-compaction appendix.
// Compaction: one atomicAdd per wave (popcount), in-wave prefix via ballot.
__global__ __launch_bounds__(256) void dense_full_compact(
        const unsigned short* __restrict__ side_h,
        unsigned short* __restrict__ ego_h,
        const unsigned short* __restrict__ wf,
        const float* __restrict__ bgc, const float* __restrict__ bbi,
        const int* __restrict__ flags, int* __restrict__ list2,
        int* __restrict__ cnt) {
    int lane = threadIdx.x & 63;
    if (blockIdx.x >= DENSE_BLOCKS) {
        int i = (blockIdx.x - DENSE_BLOCKS) * 256 + threadIdx.x;   // node id
        bool set = (i < N_NODES) && (flags[i] != 0);
        unsigned long long m = __ballot(set);
        int pc = __popcll(m);
        if (pc) {
            int base = 0;
            if (lane == 0) base = atomicAdd(cnt, pc);
            base = __shfl(base, 0);
            if (set) list2[base + __popcll(m & ((1ull << lane) - 1ull))] = i;
        }
        return;
    }
    int wave = threadIdx.x >> 6;
    int quad = lane >> 4, n = lane & 15;
    int base = (blockIdx.x * 4 + wave) * 16;
    int rA = base + n;

    f32x4 acc[4];
    dense_core(side_h + (size_t)rA * EMB, ego_h + (size_t)rA * EMB,
               wf, lane, bgc, bbi, acc);

    // epilogue: C/D layout col=lane&15, row=quad*4+reg (m89-verified)
#pragma unroll
    for (int t = 0; t < 4; ++t)
#pragma unroll
        for (int i = 0; i < 4; ++i) {
            float v = acc[t][i];
            float o = v > 0.f ? v : 0.2f * v;
            ego_h[(size_t)(base + quad * 4 + i) * EMB + t * 16 + n] = f2bf(o);
        }
}

// K4: layer-2 list spmm + layer-1 gather_norm appendix blocks
__global__ __launch_bounds__(256) void spmm_list_norm1(
        const int* __restrict__ row_ptr, const int* __restrict__ col,
        const float* __restrict__ val, const unsigned short* __restrict__ xh,
        unsigned short* __restrict__ yh, const int* __restrict__ list,
        const int* __restrict__ cntp, const int* __restrict__ users,
        const int* __restrict__ pos, const int* __restrict__ neg,
        float* __restrict__ out) {
    int lane = threadIdx.x & 63;
    if (blockIdx.x < SPMM_BLOCKS) {
        int wave = (blockIdx.x * 256 + threadIdx.x) >> 6;
        if (wave >= *cntp) return;          // wave-uniform early exit
        int row = list[wave];
        spmm_row(row, lane, row_ptr, col, val, xh, yh + (size_t)row * EMB);
        return;
    }
    // layer-1 norm: reads ego_h (xh) post-dense-1
    int b = (blockIdx.x - SPMM_BLOCKS) * 4 + (threadIdx.x >> 6);
    int node = batch_node(users, pos, neg, b);
    float v = bf2f(xh[(size_t)node * EMB + lane]);
    float s = v * v;
#pragma unroll
    for (int off = 32; off > 0; off >>= 1) s += __shfl_xor(s, off);
    float nn = fmaxf(sqrtf(s), 1e-12f);
    out[(size_t)b * 256 + 1 * EMB + lane] = v / nn;
}

// K5: layer-2 dense, list-sparsified in-place ego update. list is deduped so
// each row is owned by exactly one wave (in-place safe). Tail wave clamps.
__global__ __launch_bounds__(256) void dense_list(
        const unsigned short* __restrict__ side_h,
        unsigned short* __restrict__ ego_h,
        const unsigned short* __restrict__ wf,
        const float* __restrict__ bgc, const float* __restrict__ bbi,
        const int* __restrict__ list, const int* __restrict__ cntp) {
    int wave = threadIdx.x >> 6;
    int lane = threadIdx.x & 63;
    int quad = lane >> 4, n = lane & 15;
    int base = (blockIdx.x * 4 + wave) * 16;
    int cntv = *cntp;
    if (base >= cntv) return;

    int rA = base + n;
    rA = list[rA < cntv ? rA : cntv - 1];

    f32x4 acc[4];
    dense_core(side_h + (size_t)rA * EMB, ego_h + (size_t)rA * EMB,
               wf, lane, bgc, bbi, acc);

    int rw[4];
#pragma unroll
    for (int i = 0; i < 4; ++i) {
        int r = base + quad * 4 + i;
        rw[i] = (r < cntv) ? list[r] : -1;
    }
#pragma unroll
    for (int t = 0; t < 4; ++t)
#pragma unroll
        for (int i = 0; i < 4; ++i) {
            if (rw[i] < 0) continue;
            float v = acc[t][i];
            float o = v > 0.f ? v : 0.2f * v;
            ego_h[(size_t)rw[i] * EMB + t * 16 + n] = f2bf(o);
        }
}

// K6: fused layer-3 (spmm->LDS -> dense -> leaky+L2norm -> out) + layer-2
// norm appendix blocks. LDS row stride 72 shorts (144B): 16B-aligned rows,
// <=2-way bank aliasing (free per m136).
#define L3_BLOCKS (B3 / 64)                // 48
__global__ __launch_bounds__(256) void layer3_norm2(
        const int* __restrict__ row_ptr, const int* __restrict__ col,
        const float* __restrict__ val, const unsigned short* __restrict__ ego_h,
        const int* __restrict__ users, const int* __restrict__ pos,
        const int* __restrict__ neg, const unsigned short* __restrict__ wf,
        const float* __restrict__ bgc, const float* __restrict__ bbi,
        float* __restrict__ out) {
    __shared__ unsigned short sside[64 * 72];   // 9216 B
    int lane = threadIdx.x & 63;
    if (blockIdx.x >= L3_BLOCKS) {
        // layer-2 norm: reads ego_h post-dense-2
        int b = (blockIdx.x - L3_BLOCKS) * 4 + (threadIdx.x >> 6);
        int node = batch_node(users, pos, neg, b);
        float v = bf2f(ego_h[(size_t)node * EMB + lane]);
        float s = v * v;
#pragma unroll
        for (int off = 32; off > 0; off >>= 1) s += __shfl_xor(s, off);
        float nn = fmaxf(sqrtf(s), 1e-12f);
        out[(size_t)b * 256 + 2 * EMB + lane] = v / nn;
        return;
    }
    int wave = threadIdx.x >> 6;
    int b0 = blockIdx.x * 64;
    // phase 1: each wave spmm's 16 batch rows into LDS (dupes benign:
    // different LDS slots, identical values). ego_h is read-only here.
    for (int r = 0; r < 16; ++r) {
        int bpos = b0 + wave * 16 + r;
        int node = batch_node(users, pos, neg, bpos);
        spmm_row(node, lane, row_ptr, col, val, ego_h, &sside[(wave * 16 + r) * 72]);
    }
    __syncthreads();
    // phase 2: dense on this wave's 16 rows, A-side from LDS
    int quad = lane >> 4, n = lane & 15;
    int nodeA = batch_node(users, pos, neg, b0 + wave * 16 + n);
    f32x4 acc[4];
    dense_core(&sside[(wave * 16 + n) * 72], ego_h + (size_t)nodeA * EMB,
               wf, lane, bgc, bbi, acc);
    // fused epilogue: leaky, per-row L2 norm (row quad*4+i lives in the 16
    // lanes of this quad: reduce over n via xor 1,2,4,8), write cols 192..255
    float ov[4][4];
#pragma unroll
    for (int t = 0; t < 4; ++t)
#pragma unroll
        for (int i = 0; i < 4; ++i) {
            float v = acc[t][i];
            ov[t][i] = v > 0.f ? v : 0.2f * v;
        }
#pragma unroll
    for (int i = 0; i < 4; ++i) {
        float s = ov[0][i] * ov[0][i] + ov[1][i] * ov[1][i]
                + ov[2][i] * ov[2][i] + ov[3][i] * ov[3][i];
        s += __shfl_xor(s, 1); s += __shfl_xor(s, 2);
        s += __shfl_xor(s, 4); s += __shfl_xor(s, 8);
        float ninv = 1.f / fmaxf(sqrtf(s), 1e-12f);
        int bpos = b0 + wave * 16 + quad * 4 + i;
#pragma unroll
        for (int t = 0; t < 4; ++t)
            out[(size_t)bpos * 256 + 192 + t * 16 + n] = ov[t][i] * ninv;
    }
}

extern "C" void kernel_launch(void* const* d_in, const int* in_sizes, int n_in,
                              void* d_out, int out_size, void* d_ws, size_t ws_size,
                              hipStream_t stream) {
    const int*   users    = (const int*)d_in[0];
    const int*   pos      = (const int*)d_in[1];
    const int*   neg      = (const int*)d_in[2];
    const int*   adj_row  = (const int*)d_in[3];
    const int*   adj_col  = (const int*)d_in[4];
    const float* adj_val  = (const float*)d_in[5];
    const float* user_emb = (const float*)d_in[6];
    const float* item_emb = (const float*)d_in[7];
    // d_in[8..19]: W_gc_0, b_gc_0, W_bi_0, b_bi_0, W_gc_1, ... (4 per layer)

    unsigned short* ego_h   = (unsigned short*)d_ws;
    unsigned short* side_h  = ego_h + (size_t)N_NODES * EMB;
    int*            row_ptr = (int*)(side_h + (size_t)N_NODES * EMB);
    unsigned short* wfrag   = (unsigned short*)(row_ptr + 200704);  // 16B-aligned
    int*            flags   = (int*)(wfrag + 6 * 8 * 64 * 8);       // 49152B -> aligned
    int*            cnt     = flags + N_NODES;                       // +4 ints pad
    int*            list2   = cnt + 4;
    float*          out     = (float*)d_out;

    // K1: all setup work in one dispatch
    setup_fused<<<SETUP_BLOCKS, 256, 0, stream>>>(
        adj_row, user_emb, item_emb,
        (const float*)d_in[8],  (const float*)d_in[10], (const float*)d_in[12],
        (const float*)d_in[14], (const float*)d_in[16], (const float*)d_in[18],
        users, pos, neg, row_ptr, ego_h, wfrag, out, flags);

    // K2: layer-1 spmm + flag-set (plain stores)
    spmm_full_flags<<<SPMM_BLOCKS + B3 / 4, 256, 0, stream>>>(
        row_ptr, adj_col, adj_val, ego_h, side_h, users, pos, neg, flags);

    // K3: layer-1 dense (full, in-place) + ballot-compaction of flags->list2
    dense_full_compact<<<DENSE_BLOCKS + COMPACT_BLOCKS, 256, 0, stream>>>(
        side_h, ego_h, wfrag, (const float*)d_in[9], (const float*)d_in[11],
        flags, list2, cnt);

    // K4: layer-2 spmm (active2) + layer-1 norm
    spmm_list_norm1<<<SPMM_BLOCKS + B3 / 4, 256, 0, stream>>>(
        row_ptr, adj_col, adj_val, ego_h, side_h, list2, cnt,
        users, pos, neg, out);

    // K5: layer-2 dense (list, in-place)
    dense_list<<<DENSE_BLOCKS, 256, 0, stream>>>(
        side_h, ego_h, wfrag + (size_t)1 * 2 * 8 * 64 * 8,
        (const float*)d_in[13], (const float*)d_in[15], list2, cnt);

    // K6: fused layer-3 + layer-2 norm
    layer3_norm2<<<L3_BLOCKS + B3 / 4, 256, 0, stream>>>(
        row_ptr, adj_col, adj_val, ego_h, users, pos, neg,
        wfrag + (size_t)2 * 2 * 8 * 64 * 8,
        (const float*)d_in[17], (const float*)d_in[19], out);
}